// Round 3
// baseline (505.209 us; speedup 1.0000x reference)
//
#include <hip/hip_runtime.h>

#define B_TOT 2048
#define SEQ 64
#define CH 384
#define NH 12
#define HD 32
#define NC3 1152
#define LDP 392          // padded bf16 row stride for s_x / s_att (784 B: 16B-aligned, 2-way banks)
#define QKS 40           // q/k tile row stride in u16 (80 B: 16B-aligned, 2-way banks)
#define HDSZ 7424        // per-head u16: q 64*40 + k 64*40 + vt 32*72
#define QK_SCALE 0.17677669529663687f

typedef __attribute__((ext_vector_type(8))) short short8;   // 8 x bf16 (4 VGPR) MFMA frag
typedef __attribute__((ext_vector_type(4))) short short4v;
typedef __attribute__((ext_vector_type(4))) float f32x4;
typedef unsigned short u16;

__device__ __forceinline__ u16 f2bf(float f) {              // RNE f32->bf16
  unsigned int u = __float_as_uint(f);
  u += 0x7fffu + ((u >> 16) & 1u);
  return (u16)(u >> 16);
}

// 16B-granule XOR swizzle for the P (softmax prob) LDS tile [64][64] bf16
__device__ __forceinline__ int pswz(int row, int col) {
  return row * 64 + ((((col >> 3) ^ (row & 7)) << 3) | (col & 7));
}

// ---------------- K0: weights -> bf16 transposed [n][k]; rpb repack ----------
// rpbz layout: [h][jt][qt] blocks of 256 floats: [g4][q16][r]  (r = key j low 2 bits)
__global__ void k_prep(const float* __restrict__ qkv_w, const float* __restrict__ proj_w,
                       const float* __restrict__ rpb_table, const int* __restrict__ rpb_index,
                       u16* __restrict__ qkvwt, u16* __restrict__ projwt, float* __restrict__ rpbz)
{
  int idx = blockIdx.x * 256 + threadIdx.x;
  if (idx < CH * NC3) {
    int k = idx / NC3, n = idx - k * NC3;
    qkvwt[n * LDP + k] = f2bf(qkv_w[idx]);
    return;
  }
  idx -= CH * NC3;
  if (idx < CH * CH) {
    int k = idx / CH, n = idx - k * CH;
    projwt[n * LDP + k] = f2bf(proj_w[idx]);
    return;
  }
  idx -= CH * CH;
  if (idx < NH * SEQ * SEQ) {
    int h = idx >> 12, j = (idx >> 6) & 63, q = idx & 63;  // j = key, q = query
    int jt = j >> 4, g4j = (j >> 2) & 3, r = j & 3;
    int qt = q >> 4, q16 = q & 15;
    int dst = (h * 16 + jt * 4 + qt) * 256 + g4j * 64 + q16 * 4 + r;
    rpbz[dst] = rpb_table[rpb_index[q * 64 + j] * NH + h];
  }
}

// ---------------- K1: noise-conditioned trunk MLP -> inv(1+gate), nbias ----------------------
__global__ void k_trunk(const float* __restrict__ sigma, const float* __restrict__ w1,
                        const float* __restrict__ b1, const float* __restrict__ w2,
                        const float* __restrict__ b2, const float* __restrict__ gw,
                        const float* __restrict__ gb, const float* __restrict__ bw,
                        const float* __restrict__ bb,
                        float* __restrict__ inv1pg, float* __restrict__ nbias)
{
  int b = blockIdx.x, j = threadIdx.x;   // 64 threads
  __shared__ float sh[64];
  float ls = logf(fmaxf(sigma[b], 1e-6f));
  float z = fmaf(ls, w1[j], b1[j]);
  z = z / (1.f + __expf(-z));            // silu
  sh[j] = z;
  __syncthreads();
  float a = b2[j];
  #pragma unroll 8
  for (int i = 0; i < 64; ++i) a = fmaf(sh[i], w2[i * 64 + j], a);
  a = a / (1.f + __expf(-a));
  __syncthreads();
  sh[j] = a;
  __syncthreads();
  if (j == 0) {
    float zg = gb[0];
    #pragma unroll 8
    for (int i = 0; i < 64; ++i) zg = fmaf(sh[i], gw[i], zg);
    float gate = 1.f / (1.f + __expf(-zg));
    inv1pg[b] = 1.f / (1.f + gate);
  }
  if (j < NH) {
    float zb = bb[j];
    #pragma unroll 8
    for (int i = 0; i < 64; ++i) zb = fmaf(sh[i], bw[i * NH + j], zb);
    nbias[b * NH + j] = zb;
  }
}

// ---------------- K2: tvec = temb @ qkvt_w + qkv_b  (B x 1152) --------------------------------
__global__ __launch_bounds__(256) void k_tvec(const float* __restrict__ temb,
                                              const float* __restrict__ qkvt_w,
                                              const float* __restrict__ qkv_b,
                                              float* __restrict__ tvec)
{
  __shared__ float st[16 * 384];
  int bi = blockIdx.x;
  int brow = bi / 9, cseg = bi - brow * 9;
  int cb = cseg * 128;
  int tid = threadIdx.x;
  for (int idx = tid; idx < 16 * 384; idx += 256) {
    int r = idx / 384, k = idx - r * 384;
    st[idx] = temb[(brow * 16 + r) * 384 + k];
  }
  __syncthreads();
  int cl = tid & 127, half = tid >> 7;
  float acc[8];
  #pragma unroll
  for (int i = 0; i < 8; ++i) acc[i] = 0.f;
  #pragma unroll 4
  for (int k = 0; k < 384; ++k) {
    float w = qkvt_w[k * NC3 + cb + cl];
    #pragma unroll
    for (int i = 0; i < 8; ++i) acc[i] = fmaf(st[(half * 8 + i) * 384 + k], w, acc[i]);
  }
  float qb = qkv_b[cb + cl];
  #pragma unroll
  for (int i = 0; i < 8; ++i)
    tvec[(brow * 16 + half * 8 + i) * NC3 + cb + cl] = acc[i] + qb;
}

// ---------------- K3: fused per-batch QKV -> attention -> proj --------------------------------
// 1024 threads = 16 waves = 4 waves/SIMD; LDS 159744 B -> 1 block/CU (50% occupancy)
__global__ __launch_bounds__(1024) void k_main(
    const float* __restrict__ x, const float* __restrict__ tvec,
    const float* __restrict__ inv1pg, const float* __restrict__ nbias,
    const u16* __restrict__ qkvwt, const u16* __restrict__ projwt,
    const float* __restrict__ rpbz, const float* __restrict__ proj_b,
    float* __restrict__ out)
{
  __shared__ __align__(16) u16 s_x[64 * LDP];     // x[b] bf16, padded rows   (50176 B)
  __shared__ __align__(16) u16 s_hd[4 * HDSZ];    // per head: q[64][40] | k[64][40] | vt[32][72]  (59392 B)
  __shared__ __align__(16) u16 s_att[64 * LDP];   // attention output bf16    (50176 B)
  const f32x4 fz = {0.f, 0.f, 0.f, 0.f};

  const int b = blockIdx.x;
  const int tid = threadIdx.x;
  const int w = tid >> 6, l = tid & 63;
  const int q16 = l & 15, g4 = l >> 4;

  // ---- phase 0: stage x[b] (fp32 -> bf16), fully coalesced float4 loads ----
  {
    const float* xb = x + b * (SEQ * CH);
    #pragma unroll
    for (int it = 0; it < 6; ++it) {
      int fi = it * 1024 + tid;           // float4 index; 96 float4 per row
      int row = fi / 96, c4 = fi - row * 96;
      const float4 a = *reinterpret_cast<const float4*>(xb + fi * 4);
      short4v v;
      v[0] = (short)f2bf(a.x); v[1] = (short)f2bf(a.y);
      v[2] = (short)f2bf(a.z); v[3] = (short)f2bf(a.w);
      *reinterpret_cast<short4v*>(&s_x[row * LDP + c4 * 4]) = v;
    }
  }
  __syncthreads();

  const float inv = inv1pg[b];
  const int mhalf = w & 1;                 // m-half for phases A/C
  const int ntb = (w >> 1) * 3;            // first n-tile for phases A/C

  for (int g = 0; g < 3; ++g) {
    // ================= phase A: qkv GEMM for heads g*4..g*4+3 =================
    // 24 n-tiles of 16 cols x 2 m-halves = 48 wave-tasks
    float tv[3]; const u16* bp[3]; int mh6[3], hj6[3], hf6[3];
    #pragma unroll
    for (int i = 0; i < 3; ++i) {
      int nt = ntb + i;
      int mh = nt >> 3, hj = (nt & 7) >> 1, hf = nt & 1;
      mh6[i] = mh; hj6[i] = hj; hf6[i] = hf;
      int c = mh * CH + (g * 4 + hj) * HD + hf * 16 + q16;
      tv[i] = tvec[b * NC3 + c];
      bp[i] = qkvwt + c * LDP + g4 * 8;
    }
    f32x4 acc[2][3];
    #pragma unroll
    for (int m = 0; m < 2; ++m)
      #pragma unroll
      for (int i = 0; i < 3; ++i) acc[m][i] = fz;
    #pragma unroll 2
    for (int kt = 0; kt < 12; ++kt) {
      short8 af[2];
      #pragma unroll
      for (int m = 0; m < 2; ++m)
        af[m] = *reinterpret_cast<const short8*>(
            &s_x[((mhalf * 2 + m) * 16 + q16) * LDP + kt * 32 + g4 * 8]);
      #pragma unroll
      for (int i = 0; i < 3; ++i) {
        short8 bf = *reinterpret_cast<const short8*>(bp[i] + kt * 32);
        #pragma unroll
        for (int m = 0; m < 2; ++m)
          acc[m][i] = __builtin_amdgcn_mfma_f32_16x16x32_bf16(af[m], bf, acc[m][i], 0, 0, 0);
      }
    }
    // epilogue: +tvec, q-scale, write q/k row-major (stride 40), v transposed
    #pragma unroll
    for (int i = 0; i < 3; ++i) {
      u16* hbase = &s_hd[hj6[i] * HDSZ];
      int cof = hf6[i] * 16 + q16;
      #pragma unroll
      for (int m = 0; m < 2; ++m) {
        int mrow = (mhalf * 2 + m) * 16 + g4 * 4;
        f32x4 a = acc[m][i];
        if (mh6[i] == 0) {
          #pragma unroll
          for (int r = 0; r < 4; ++r)
            hbase[(mrow + r) * QKS + cof] = f2bf((a[r] + tv[i]) * QK_SCALE);
        } else if (mh6[i] == 1) {
          #pragma unroll
          for (int r = 0; r < 4; ++r)
            hbase[2560 + (mrow + r) * QKS + cof] = f2bf(a[r] + tv[i]);
        } else {
          short4v pk;
          #pragma unroll
          for (int r = 0; r < 4; ++r) pk[r] = (short)f2bf(a[r] + tv[i]);
          *reinterpret_cast<short4v*>(&hbase[5120 + cof * 72 + mrow]) = pk;
        }
      }
    }
    __syncthreads();

    // ================= phase B: attention, 4 waves per head (one qt each) =================
    {
      const int hh = w >> 2;               // head within group
      const int qt = w & 3;                // query tile
      const int h = g * 4 + hh;
      u16* sq = &s_hd[hh * HDSZ];
      const u16* sk = sq + 2560;
      const u16* svt = sq + 5120;
      const float nb = nbias[b * NH + h];

      // rpb prefetch (issued before the MFMAs; L2 latency hides under them)
      float4 rp4[4];
      #pragma unroll
      for (int jt = 0; jt < 4; ++jt)
        rp4[jt] = *reinterpret_cast<const float4*>(
            &rpbz[(h * 16 + jt * 4 + qt) * 256 + g4 * 64 + q16 * 4]);

      short8 bq = *reinterpret_cast<const short8*>(&sq[(qt * 16 + q16) * QKS + g4 * 8]);

      // S^T = K . Q^T : D rows = keys j, cols = queries q
      f32x4 st[4];
      #pragma unroll
      for (int jt = 0; jt < 4; ++jt) {
        short8 ak = *reinterpret_cast<const short8*>(&sk[(jt * 16 + q16) * QKS + g4 * 8]);
        st[jt] = __builtin_amdgcn_mfma_f32_16x16x32_bf16(ak, bq, fz, 0, 0, 0);
      }
      // gate + rpb + softmax (in-register; rows live on lanes {q,q+16,q+32,q+48})
      {
        float mx = -1e30f;
        #pragma unroll
        for (int jt = 0; jt < 4; ++jt)
          #pragma unroll
          for (int r = 0; r < 4; ++r) {
            float s = fmaf(st[jt][r], inv, fmaf(rp4[jt][r], inv, nb));
            st[jt][r] = s;
            mx = fmaxf(mx, s);
          }
        mx = fmaxf(mx, __shfl_xor(mx, 16));
        mx = fmaxf(mx, __shfl_xor(mx, 32));
        float sum = 0.f;
        #pragma unroll
        for (int jt = 0; jt < 4; ++jt)
          #pragma unroll
          for (int r = 0; r < 4; ++r) {
            float p = __expf(st[jt][r] - mx);
            st[jt][r] = p;
            sum += p;
          }
        sum += __shfl_xor(sum, 16);
        sum += __shfl_xor(sum, 32);
        float rn = 1.f / sum;
        #pragma unroll
        for (int jt = 0; jt < 4; ++jt)
          #pragma unroll
          for (int r = 0; r < 4; ++r) st[jt][r] *= rn;
      }
      // all q/k fragment READS (all 4 waves of this head) must finish before the
      // P overlay writes below -> block-wide barrier
      __syncthreads();
      u16* P = sq;                         // P overlays q+k region (64x64 bf16, swizzled)
      #pragma unroll
      for (int jt = 0; jt < 4; ++jt) {
        int row = qt * 16 + q16, col = jt * 16 + g4 * 4;
        short4v pk;
        #pragma unroll
        for (int r = 0; r < 4; ++r) pk[r] = (short)f2bf(st[jt][r]);
        *reinterpret_cast<short4v*>(&P[pswz(row, col)]) = pk;
      }
      // PV: out = P . V  (own rows only -> same-wave ordering suffices)
      f32x4 o[2];
      o[0] = fz; o[1] = fz;
      #pragma unroll
      for (int kk = 0; kk < 2; ++kk) {
        short8 ap = *reinterpret_cast<const short8*>(
            &P[pswz(qt * 16 + q16, kk * 32 + g4 * 8)]);
        #pragma unroll
        for (int dt = 0; dt < 2; ++dt) {
          short8 bv = *reinterpret_cast<const short8*>(&svt[(dt * 16 + q16) * 72 + kk * 32 + g4 * 8]);
          o[dt] = __builtin_amdgcn_mfma_f32_16x16x32_bf16(ap, bv, o[dt], 0, 0, 0);
        }
      }
      #pragma unroll
      for (int dt = 0; dt < 2; ++dt)
        #pragma unroll
        for (int r = 0; r < 4; ++r)
          s_att[(qt * 16 + g4 * 4 + r) * LDP + h * HD + dt * 16 + q16] = f2bf(o[dt][r]);
    }
    __syncthreads();
  }

  // ================= phase C: proj GEMM + bias -> d_out =================
  {
    const u16* bpw[3]; float pb[3]; int c6[3];
    #pragma unroll
    for (int i = 0; i < 3; ++i) {
      int c = (ntb + i) * 16 + q16;
      c6[i] = c;
      pb[i] = proj_b[c];
      bpw[i] = projwt + c * LDP + g4 * 8;
    }
    f32x4 acc[2][3];
    #pragma unroll
    for (int m = 0; m < 2; ++m)
      #pragma unroll
      for (int i = 0; i < 3; ++i) acc[m][i] = fz;
    #pragma unroll 2
    for (int kt = 0; kt < 12; ++kt) {
      short8 af[2];
      #pragma unroll
      for (int m = 0; m < 2; ++m)
        af[m] = *reinterpret_cast<const short8*>(
            &s_att[((mhalf * 2 + m) * 16 + q16) * LDP + kt * 32 + g4 * 8]);
      #pragma unroll
      for (int i = 0; i < 3; ++i) {
        short8 bf = *reinterpret_cast<const short8*>(bpw[i] + kt * 32);
        #pragma unroll
        for (int m = 0; m < 2; ++m)
          acc[m][i] = __builtin_amdgcn_mfma_f32_16x16x32_bf16(af[m], bf, acc[m][i], 0, 0, 0);
      }
    }
    float* ob = out + b * (SEQ * CH);
    #pragma unroll
    for (int i = 0; i < 3; ++i)
      #pragma unroll
      for (int m = 0; m < 2; ++m)
        #pragma unroll
        for (int r = 0; r < 4; ++r)
          ob[((mhalf * 2 + m) * 16 + g4 * 4 + r) * CH + c6[i]] = acc[m][i][r] + pb[i];
  }
}

// ---------------- launcher ----------------
extern "C" void kernel_launch(void* const* d_in, const int* in_sizes, int n_in,
                              void* d_out, int out_size, void* d_ws, size_t ws_size,
                              hipStream_t stream) {
  const float* x       = (const float*)d_in[0];
  const float* temb    = (const float*)d_in[1];
  const float* sigma   = (const float*)d_in[2];
  const float* qkv_w   = (const float*)d_in[3];
  const float* qkv_b   = (const float*)d_in[4];
  const float* qkvt_w  = (const float*)d_in[5];
  const float* w1      = (const float*)d_in[6];
  const float* b1      = (const float*)d_in[7];
  const float* w2      = (const float*)d_in[8];
  const float* b2      = (const float*)d_in[9];
  const float* gw      = (const float*)d_in[10];
  const float* gb      = (const float*)d_in[11];
  const float* bw      = (const float*)d_in[12];
  const float* bb      = (const float*)d_in[13];
  const float* proj_w  = (const float*)d_in[14];
  const float* proj_b  = (const float*)d_in[15];
  const float* rpb_tab = (const float*)d_in[16];
  const int*   rpb_idx = (const int*)d_in[17];
  float* out = (float*)d_out;

  char* ws = (char*)d_ws;
  float* tvec   = (float*)(ws);                    // 2048*1152*4 = 9437184
  float* inv1pg = (float*)(ws + 9437184);          // 8192
  float* nbias  = (float*)(ws + 9445376);          // 98304
  u16*   qkvwt  = (u16*)  (ws + 9543680);          // 1152*392*2 = 903168
  u16*   projwt = (u16*)  (ws + 10446848);         // 384*392*2  = 301056
  float* rpbz   = (float*)(ws + 10747904);         // 12*64*64*4 = 196608  (total 10944512 B)

  k_prep<<<2496, 256, 0, stream>>>(qkv_w, proj_w, rpb_tab, rpb_idx, qkvwt, projwt, rpbz);
  k_trunk<<<2048, 64, 0, stream>>>(sigma, w1, b1, w2, b2, gw, gb, bw, bb, inv1pg, nbias);
  k_tvec<<<1152, 256, 0, stream>>>(temb, qkvt_w, qkv_b, tvec);
  k_main<<<2048, 1024, 0, stream>>>(x, tvec, inv1pg, nbias, qkvwt, projwt, rpbz, proj_b, out);
}

// Round 4
// 470.264 us; speedup vs baseline: 1.0743x; 1.0743x over previous
//
#include <hip/hip_runtime.h>

#define B_TOT 2048
#define SEQ 64
#define CH 384
#define NH 12
#define HD 32
#define NC3 1152
#define LDP 392          // padded bf16 row stride for s_x / s_att / weights
#define QKS 40           // q/k tile row stride in u16 (80 B, 16B-aligned)
#define HDSZ 7424        // per-head u16: q 64*40 + k 64*40 + vt 32*72
#define QK_SCALE 0.17677669529663687f

typedef __attribute__((ext_vector_type(8))) short short8;   // 8 x bf16 (4 VGPR) MFMA frag
typedef __attribute__((ext_vector_type(4))) short short4v;
typedef __attribute__((ext_vector_type(4))) float f32x4;
typedef unsigned short u16;

__device__ __forceinline__ u16 f2bf(float f) {              // RNE f32->bf16
  unsigned int u = __float_as_uint(f);
  u += 0x7fffu + ((u >> 16) & 1u);
  return (u16)(u >> 16);
}

// 16B-granule XOR swizzle for the P (softmax prob) LDS tile [64][64] bf16
__device__ __forceinline__ int pswz(int row, int col) {
  return row * 64 + ((((col >> 3) ^ (row & 7)) << 3) | (col & 7));
}

// ---------------- K0: weights -> bf16 transposed [n][k]; rpb repack ----------
// rpbz layout: [h][jt][qt] blocks of 256 floats: [g4][q16][r]  (r = key j low 2 bits)
__global__ void k_prep(const float* __restrict__ qkv_w, const float* __restrict__ proj_w,
                       const float* __restrict__ rpb_table, const int* __restrict__ rpb_index,
                       u16* __restrict__ qkvwt, u16* __restrict__ projwt, float* __restrict__ rpbz)
{
  int idx = blockIdx.x * 256 + threadIdx.x;
  if (idx < CH * NC3) {
    int k = idx / NC3, n = idx - k * NC3;
    qkvwt[n * LDP + k] = f2bf(qkv_w[idx]);
    return;
  }
  idx -= CH * NC3;
  if (idx < CH * CH) {
    int k = idx / CH, n = idx - k * CH;
    projwt[n * LDP + k] = f2bf(proj_w[idx]);
    return;
  }
  idx -= CH * CH;
  if (idx < NH * SEQ * SEQ) {
    int h = idx >> 12, j = (idx >> 6) & 63, q = idx & 63;  // j = key, q = query
    int jt = j >> 4, g4j = (j >> 2) & 3, r = j & 3;
    int qt = q >> 4, q16 = q & 15;
    int dst = (h * 16 + jt * 4 + qt) * 256 + g4j * 64 + q16 * 4 + r;
    rpbz[dst] = rpb_table[rpb_index[q * 64 + j] * NH + h];
  }
}

// ---------------- K1: noise-conditioned trunk MLP -> inv(1+gate), nbias ----------------------
__global__ void k_trunk(const float* __restrict__ sigma, const float* __restrict__ w1,
                        const float* __restrict__ b1, const float* __restrict__ w2,
                        const float* __restrict__ b2, const float* __restrict__ gw,
                        const float* __restrict__ gb, const float* __restrict__ bw,
                        const float* __restrict__ bb,
                        float* __restrict__ inv1pg, float* __restrict__ nbias)
{
  int b = blockIdx.x, j = threadIdx.x;   // 64 threads
  __shared__ float sh[64];
  float ls = logf(fmaxf(sigma[b], 1e-6f));
  float z = fmaf(ls, w1[j], b1[j]);
  z = z / (1.f + __expf(-z));            // silu
  sh[j] = z;
  __syncthreads();
  float a = b2[j];
  #pragma unroll 8
  for (int i = 0; i < 64; ++i) a = fmaf(sh[i], w2[i * 64 + j], a);
  a = a / (1.f + __expf(-a));
  __syncthreads();
  sh[j] = a;
  __syncthreads();
  if (j == 0) {
    float zg = gb[0];
    #pragma unroll 8
    for (int i = 0; i < 64; ++i) zg = fmaf(sh[i], gw[i], zg);
    float gate = 1.f / (1.f + __expf(-zg));
    inv1pg[b] = 1.f / (1.f + gate);
  }
  if (j < NH) {
    float zb = bb[j];
    #pragma unroll 8
    for (int i = 0; i < 64; ++i) zb = fmaf(sh[i], bw[i * NH + j], zb);
    nbias[b * NH + j] = zb;
  }
}

// ---------------- K2: tvec = temb @ qkvt_w + qkv_b  (B x 1152) --------------------------------
__global__ __launch_bounds__(256) void k_tvec(const float* __restrict__ temb,
                                              const float* __restrict__ qkvt_w,
                                              const float* __restrict__ qkv_b,
                                              float* __restrict__ tvec)
{
  __shared__ float st[16 * 384];
  int bi = blockIdx.x;
  int brow = bi / 9, cseg = bi - brow * 9;
  int cb = cseg * 128;
  int tid = threadIdx.x;
  for (int idx = tid; idx < 16 * 384; idx += 256) {
    int r = idx / 384, k = idx - r * 384;
    st[idx] = temb[(brow * 16 + r) * 384 + k];
  }
  __syncthreads();
  int cl = tid & 127, half = tid >> 7;
  float acc[8];
  #pragma unroll
  for (int i = 0; i < 8; ++i) acc[i] = 0.f;
  #pragma unroll 4
  for (int k = 0; k < 384; ++k) {
    float w = qkvt_w[k * NC3 + cb + cl];
    #pragma unroll
    for (int i = 0; i < 8; ++i) acc[i] = fmaf(st[(half * 8 + i) * 384 + k], w, acc[i]);
  }
  float qb = qkv_b[cb + cl];
  #pragma unroll
  for (int i = 0; i < 8; ++i)
    tvec[(brow * 16 + half * 8 + i) * NC3 + cb + cl] = acc[i] + qb;
}

// ---------------- K3: fused per-batch QKV -> attention -> proj --------------------------------
// 512 threads = 8 waves = 2 waves/SIMD; LDS 159744 B -> 1 block/CU.
// Phases A/C use an explicit depth-2 register prefetch pipeline on the L2 weight
// fragments (the measured bottleneck: dependent L2-load -> MFMA chains).
__global__ __launch_bounds__(512) void k_main(
    const float* __restrict__ x, const float* __restrict__ tvec,
    const float* __restrict__ inv1pg, const float* __restrict__ nbias,
    const u16* __restrict__ qkvwt, const u16* __restrict__ projwt,
    const float* __restrict__ rpbz, const float* __restrict__ proj_b,
    float* __restrict__ out)
{
  __shared__ __align__(16) u16 s_x[64 * LDP];     // x[b] bf16   (50176 B)
  __shared__ __align__(16) u16 s_hd[4 * HDSZ];    // per head: q[64][40] | k[64][40] | vt[32][72]  (59392 B)
  __shared__ __align__(16) u16 s_att[64 * LDP];   // attention output bf16 (50176 B)
  const f32x4 fz = {0.f, 0.f, 0.f, 0.f};

  const int b = blockIdx.x;
  const int tid = threadIdx.x;
  const int w = tid >> 6, l = tid & 63;
  const int q16 = l & 15, g4 = l >> 4;

  // ---- phase 0: stage x[b] (fp32 -> bf16), fully coalesced float4 loads ----
  {
    const float* xb = x + b * (SEQ * CH);
    #pragma unroll
    for (int it = 0; it < 12; ++it) {
      int fi = it * 512 + tid;            // float4 index; 96 float4 per row
      int row = fi / 96, c4 = fi - row * 96;
      const float4 a = *reinterpret_cast<const float4*>(xb + fi * 4);
      short4v v;
      v[0] = (short)f2bf(a.x); v[1] = (short)f2bf(a.y);
      v[2] = (short)f2bf(a.z); v[3] = (short)f2bf(a.w);
      *reinterpret_cast<short4v*>(&s_x[row * LDP + c4 * 4]) = v;
    }
  }
  __syncthreads();

  const float inv = inv1pg[b];

  for (int g = 0; g < 3; ++g) {
    // ================= phase A: qkv GEMM for heads g*4..g*4+3 =================
    // 24 n-tiles of 16 cols; wave w owns tiles w*3..w*3+2, all 4 m-tiles
    float tv[3]; const u16* bp[3]; int mh6[3], hj6[3], hf6[3];
    #pragma unroll
    for (int i = 0; i < 3; ++i) {
      int nt = w * 3 + i;
      int mh = nt >> 3, hj = (nt & 7) >> 1, hf = nt & 1;
      mh6[i] = mh; hj6[i] = hj; hf6[i] = hf;
      int c = mh * CH + (g * 4 + hj) * HD + hf * 16 + q16;
      tv[i] = tvec[b * NC3 + c];
      bp[i] = qkvwt + c * LDP + g4 * 8;
    }
    f32x4 acc[4][3];
    #pragma unroll
    for (int m = 0; m < 4; ++m)
      #pragma unroll
      for (int i = 0; i < 3; ++i) acc[m][i] = fz;

    short8 pA[3], pB[3];                  // depth-2 weight prefetch (static rotation)
    #pragma unroll
    for (int i = 0; i < 3; ++i) pA[i] = *reinterpret_cast<const short8*>(bp[i]);
    #pragma unroll
    for (int i = 0; i < 3; ++i) pB[i] = *reinterpret_cast<const short8*>(bp[i] + 32);

    #pragma unroll
    for (int kt2 = 0; kt2 < 6; ++kt2) {
      {  // even step: kt = 2*kt2, frags in pA; refill with kt+2
        short8 af[4];
        #pragma unroll
        for (int m = 0; m < 4; ++m)
          af[m] = *reinterpret_cast<const short8*>(&s_x[(m * 16 + q16) * LDP + kt2 * 64 + g4 * 8]);
        #pragma unroll
        for (int i = 0; i < 3; ++i) {
          short8 bf = pA[i];
          if (kt2 < 5) pA[i] = *reinterpret_cast<const short8*>(bp[i] + (kt2 * 2 + 2) * 32);
          #pragma unroll
          for (int m = 0; m < 4; ++m)
            acc[m][i] = __builtin_amdgcn_mfma_f32_16x16x32_bf16(af[m], bf, acc[m][i], 0, 0, 0);
        }
      }
      {  // odd step: kt = 2*kt2+1, frags in pB; refill with kt+2
        short8 af[4];
        #pragma unroll
        for (int m = 0; m < 4; ++m)
          af[m] = *reinterpret_cast<const short8*>(&s_x[(m * 16 + q16) * LDP + kt2 * 64 + 32 + g4 * 8]);
        #pragma unroll
        for (int i = 0; i < 3; ++i) {
          short8 bf = pB[i];
          if (kt2 < 5) pB[i] = *reinterpret_cast<const short8*>(bp[i] + (kt2 * 2 + 3) * 32);
          #pragma unroll
          for (int m = 0; m < 4; ++m)
            acc[m][i] = __builtin_amdgcn_mfma_f32_16x16x32_bf16(af[m], bf, acc[m][i], 0, 0, 0);
        }
      }
    }
    // epilogue: +tvec, q-scale, write q/k row-major (stride 40), v transposed
    #pragma unroll
    for (int i = 0; i < 3; ++i) {
      u16* hbase = &s_hd[hj6[i] * HDSZ];
      int cof = hf6[i] * 16 + q16;
      #pragma unroll
      for (int m = 0; m < 4; ++m) {
        int mrow = m * 16 + g4 * 4;
        f32x4 a = acc[m][i];
        if (mh6[i] == 0) {
          #pragma unroll
          for (int r = 0; r < 4; ++r)
            hbase[(mrow + r) * QKS + cof] = f2bf((a[r] + tv[i]) * QK_SCALE);
        } else if (mh6[i] == 1) {
          #pragma unroll
          for (int r = 0; r < 4; ++r)
            hbase[2560 + (mrow + r) * QKS + cof] = f2bf(a[r] + tv[i]);
        } else {
          short4v pk;
          #pragma unroll
          for (int r = 0; r < 4; ++r) pk[r] = (short)f2bf(a[r] + tv[i]);
          *reinterpret_cast<short4v*>(&hbase[5120 + cof * 72 + mrow]) = pk;
        }
      }
    }
    __syncthreads();

    // ================= phase B: attention, 2 waves per head =================
    {
      const int hh = w >> 1;               // head within group
      const int half = w & 1;              // query-tile pair: qt = half*2 + {0,1}
      const int h = g * 4 + hh;
      u16* sq = &s_hd[hh * HDSZ];
      const u16* sk = sq + 2560;
      const u16* svt = sq + 5120;
      const float nb = nbias[b * NH + h];

      // rpb prefetch (issued before the MFMAs; L2 latency hides under them)
      float4 rp4[4][2];
      #pragma unroll
      for (int jt = 0; jt < 4; ++jt)
        #pragma unroll
        for (int qtl = 0; qtl < 2; ++qtl)
          rp4[jt][qtl] = *reinterpret_cast<const float4*>(
              &rpbz[(h * 16 + jt * 4 + (half * 2 + qtl)) * 256 + g4 * 64 + q16 * 4]);

      short8 bq[2];
      #pragma unroll
      for (int qtl = 0; qtl < 2; ++qtl)
        bq[qtl] = *reinterpret_cast<const short8*>(
            &sq[(half * 32 + qtl * 16 + q16) * QKS + g4 * 8]);

      // S^T = K . Q^T : D rows = keys j, cols = queries q
      f32x4 st[4][2];
      #pragma unroll
      for (int jt = 0; jt < 4; ++jt) {
        short8 ak = *reinterpret_cast<const short8*>(&sk[(jt * 16 + q16) * QKS + g4 * 8]);
        #pragma unroll
        for (int qtl = 0; qtl < 2; ++qtl)
          st[jt][qtl] = __builtin_amdgcn_mfma_f32_16x16x32_bf16(ak, bq[qtl], fz, 0, 0, 0);
      }
      // gate + rpb + softmax (in-register; rows live on lanes {q,q+16,q+32,q+48})
      #pragma unroll
      for (int qtl = 0; qtl < 2; ++qtl) {
        float mx = -1e30f;
        #pragma unroll
        for (int jt = 0; jt < 4; ++jt)
          #pragma unroll
          for (int r = 0; r < 4; ++r) {
            float s = fmaf(st[jt][qtl][r], inv, fmaf(rp4[jt][qtl][r], inv, nb));
            st[jt][qtl][r] = s;
            mx = fmaxf(mx, s);
          }
        mx = fmaxf(mx, __shfl_xor(mx, 16));
        mx = fmaxf(mx, __shfl_xor(mx, 32));
        float sum = 0.f;
        #pragma unroll
        for (int jt = 0; jt < 4; ++jt)
          #pragma unroll
          for (int r = 0; r < 4; ++r) {
            float p = __expf(st[jt][qtl][r] - mx);
            st[jt][qtl][r] = p;
            sum += p;
          }
        sum += __shfl_xor(sum, 16);
        sum += __shfl_xor(sum, 32);
        float rn = 1.f / sum;
        #pragma unroll
        for (int jt = 0; jt < 4; ++jt)
          #pragma unroll
          for (int r = 0; r < 4; ++r) st[jt][qtl][r] *= rn;
      }
      // all q/k fragment READS (both waves of this head) must finish before the
      // P overlay writes below -> block-wide barrier
      __syncthreads();
      u16* P = sq;                         // P overlays q+k region (64x64 bf16, swizzled)
      #pragma unroll
      for (int qtl = 0; qtl < 2; ++qtl)
        #pragma unroll
        for (int jt = 0; jt < 4; ++jt) {
          int row = half * 32 + qtl * 16 + q16, col = jt * 16 + g4 * 4;
          short4v pk;
          #pragma unroll
          for (int r = 0; r < 4; ++r) pk[r] = (short)f2bf(st[jt][qtl][r]);
          *reinterpret_cast<short4v*>(&P[pswz(row, col)]) = pk;
        }
      // PV: out = P . V  (own rows only -> no barrier needed; V transposed in LDS)
      f32x4 o[2][2];
      #pragma unroll
      for (int qtl = 0; qtl < 2; ++qtl) { o[qtl][0] = fz; o[qtl][1] = fz; }
      #pragma unroll
      for (int kk = 0; kk < 2; ++kk) {
        short8 bv[2];
        #pragma unroll
        for (int dt = 0; dt < 2; ++dt)
          bv[dt] = *reinterpret_cast<const short8*>(&svt[(dt * 16 + q16) * 72 + kk * 32 + g4 * 8]);
        #pragma unroll
        for (int qtl = 0; qtl < 2; ++qtl) {
          short8 ap = *reinterpret_cast<const short8*>(
              &P[pswz(half * 32 + qtl * 16 + q16, kk * 32 + g4 * 8)]);
          #pragma unroll
          for (int dt = 0; dt < 2; ++dt)
            o[qtl][dt] = __builtin_amdgcn_mfma_f32_16x16x32_bf16(ap, bv[dt], o[qtl][dt], 0, 0, 0);
        }
      }
      #pragma unroll
      for (int qtl = 0; qtl < 2; ++qtl)
        #pragma unroll
        for (int dt = 0; dt < 2; ++dt)
          #pragma unroll
          for (int r = 0; r < 4; ++r)
            s_att[(half * 32 + qtl * 16 + g4 * 4 + r) * LDP + h * HD + dt * 16 + q16] =
                f2bf(o[qtl][dt][r]);
    }
    __syncthreads();
  }

  // ================= phase C: proj GEMM + bias -> d_out (same prefetch pipeline) =================
  {
    const u16* bpw[3]; float pb[3]; int c6[3];
    #pragma unroll
    for (int i = 0; i < 3; ++i) {
      int c = w * 48 + i * 16 + q16;
      c6[i] = c;
      pb[i] = proj_b[c];
      bpw[i] = projwt + c * LDP + g4 * 8;
    }
    f32x4 acc[4][3];
    #pragma unroll
    for (int m = 0; m < 4; ++m)
      #pragma unroll
      for (int i = 0; i < 3; ++i) acc[m][i] = fz;

    short8 pA[3], pB[3];
    #pragma unroll
    for (int i = 0; i < 3; ++i) pA[i] = *reinterpret_cast<const short8*>(bpw[i]);
    #pragma unroll
    for (int i = 0; i < 3; ++i) pB[i] = *reinterpret_cast<const short8*>(bpw[i] + 32);

    #pragma unroll
    for (int kt2 = 0; kt2 < 6; ++kt2) {
      {  // even step
        short8 af[4];
        #pragma unroll
        for (int m = 0; m < 4; ++m)
          af[m] = *reinterpret_cast<const short8*>(&s_att[(m * 16 + q16) * LDP + kt2 * 64 + g4 * 8]);
        #pragma unroll
        for (int i = 0; i < 3; ++i) {
          short8 bf = pA[i];
          if (kt2 < 5) pA[i] = *reinterpret_cast<const short8*>(bpw[i] + (kt2 * 2 + 2) * 32);
          #pragma unroll
          for (int m = 0; m < 4; ++m)
            acc[m][i] = __builtin_amdgcn_mfma_f32_16x16x32_bf16(af[m], bf, acc[m][i], 0, 0, 0);
        }
      }
      {  // odd step
        short8 af[4];
        #pragma unroll
        for (int m = 0; m < 4; ++m)
          af[m] = *reinterpret_cast<const short8*>(&s_att[(m * 16 + q16) * LDP + kt2 * 64 + 32 + g4 * 8]);
        #pragma unroll
        for (int i = 0; i < 3; ++i) {
          short8 bf = pB[i];
          if (kt2 < 5) pB[i] = *reinterpret_cast<const short8*>(bpw[i] + (kt2 * 2 + 3) * 32);
          #pragma unroll
          for (int m = 0; m < 4; ++m)
            acc[m][i] = __builtin_amdgcn_mfma_f32_16x16x32_bf16(af[m], bf, acc[m][i], 0, 0, 0);
        }
      }
    }
    float* ob = out + b * (SEQ * CH);
    #pragma unroll
    for (int i = 0; i < 3; ++i)
      #pragma unroll
      for (int m = 0; m < 4; ++m)
        #pragma unroll
        for (int r = 0; r < 4; ++r)
          ob[(m * 16 + g4 * 4 + r) * CH + c6[i]] = acc[m][i][r] + pb[i];
  }
}

// ---------------- launcher ----------------
extern "C" void kernel_launch(void* const* d_in, const int* in_sizes, int n_in,
                              void* d_out, int out_size, void* d_ws, size_t ws_size,
                              hipStream_t stream) {
  const float* x       = (const float*)d_in[0];
  const float* temb    = (const float*)d_in[1];
  const float* sigma   = (const float*)d_in[2];
  const float* qkv_w   = (const float*)d_in[3];
  const float* qkv_b   = (const float*)d_in[4];
  const float* qkvt_w  = (const float*)d_in[5];
  const float* w1      = (const float*)d_in[6];
  const float* b1      = (const float*)d_in[7];
  const float* w2      = (const float*)d_in[8];
  const float* b2      = (const float*)d_in[9];
  const float* gw      = (const float*)d_in[10];
  const float* gb      = (const float*)d_in[11];
  const float* bw      = (const float*)d_in[12];
  const float* bb      = (const float*)d_in[13];
  const float* proj_w  = (const float*)d_in[14];
  const float* proj_b  = (const float*)d_in[15];
  const float* rpb_tab = (const float*)d_in[16];
  const int*   rpb_idx = (const int*)d_in[17];
  float* out = (float*)d_out;

  char* ws = (char*)d_ws;
  float* tvec   = (float*)(ws);                    // 2048*1152*4 = 9437184
  float* inv1pg = (float*)(ws + 9437184);          // 8192
  float* nbias  = (float*)(ws + 9445376);          // 98304
  u16*   qkvwt  = (u16*)  (ws + 9543680);          // 1152*392*2 = 903168
  u16*   projwt = (u16*)  (ws + 10446848);         // 384*392*2  = 301056
  float* rpbz   = (float*)(ws + 10747904);         // 12*64*64*4 = 196608  (total 10944512 B)

  k_prep<<<2496, 256, 0, stream>>>(qkv_w, proj_w, rpb_tab, rpb_idx, qkvwt, projwt, rpbz);
  k_trunk<<<2048, 64, 0, stream>>>(sigma, w1, b1, w2, b2, gw, gb, bw, bb, inv1pg, nbias);
  k_tvec<<<1152, 256, 0, stream>>>(temb, qkvt_w, qkv_b, tvec);
  k_main<<<2048, 512, 0, stream>>>(x, tvec, inv1pg, nbias, qkvwt, projwt, rpbz, proj_b, out);
}